// Round 1
// baseline (861.190 us; speedup 1.0000x reference)
//
#include <hip/hip_runtime.h>

// PackedViterbi: V_new[i] = logsumexp_j(theta[t,b,i,j] + V[j]) scanned over t,
// then out[b] = logsumexp_i V[i].  T=512, B=64, S=64, theta fp32.
//
// Decomposition: one block per sequence b (the t-scan is sequential).
// Block = 1024 threads = 16 waves; wave w owns rows 4w..4w+3; each row is
// handled by a 16-lane subgroup, each lane holding 4 consecutive columns
// (one float4 -> global_load_dwordx4, coalesced, prefetched 1 step ahead).
// V kept in double-buffered LDS; one barrier per step.

constexpr int T_DIM = 512;
constexpr int B_DIM = 64;
constexpr int S_DIM = 64;

__global__ __launch_bounds__(1024, 1) void packed_viterbi_kernel(
    const float* __restrict__ theta,
    const int* __restrict__ lengths,
    float* __restrict__ out)
{
    const int b    = blockIdx.x;
    const int tid  = threadIdx.x;
    const int wave = tid >> 6;        // 0..15
    const int lane = tid & 63;
    const int sub  = lane & 15;       // position within row subgroup
    const int rloc = lane >> 4;       // 0..3 local row within wave
    const int row  = (wave << 2) + rloc;

    const int L = lengths[b];         // 1..T

    __shared__ float Vbuf[2][S_DIM];
    if (tid < S_DIM) Vbuf[0][tid] = 0.0f;
    __syncthreads();

    const size_t t_stride = (size_t)B_DIM * S_DIM * S_DIM;   // elements per t
    const float* base = theta + (size_t)b * (S_DIM * S_DIM)
                              + (size_t)wave * 256 + (size_t)lane * 4;

    // software pipeline: prefetch step t+1 while computing step t
    float4 pre = *(const float4*)base;    // t = 0
    int cur = 0;

    for (int t = 0; t < L; ++t) {
        const float4 th = pre;
        if (t + 1 < L) {
            pre = *(const float4*)(base + (size_t)(t + 1) * t_stride);
        }

        // V for this lane's 4 columns (broadcast across the 4 row-subgroups)
        const float4 Vq = *(const float4*)&Vbuf[cur][sub * 4];

        // m = max over all 64 V entries (each 16-lane subgroup spans all j)
        float m = fmaxf(fmaxf(Vq.x, Vq.y), fmaxf(Vq.z, Vq.w));
        #pragma unroll
        for (int off = 1; off < 16; off <<= 1)
            m = fmaxf(m, __shfl_xor(m, off, 64));

        // s = sum_j exp(theta[i,j] + V[j] - m); theta<=~6, V-m<=0 -> safe
        float s = __expf(th.x + (Vq.x - m))
                + __expf(th.y + (Vq.y - m))
                + __expf(th.z + (Vq.z - m))
                + __expf(th.w + (Vq.w - m));
        #pragma unroll
        for (int off = 1; off < 16; off <<= 1)
            s += __shfl_xor(s, off, 64);

        const float vn = m + __logf(s);
        if (sub == 0) Vbuf[cur ^ 1][row] = vn;
        __syncthreads();
        cur ^= 1;
    }

    // Terminal logsumexp over states, wave 0 only
    if (wave == 0) {
        float v = Vbuf[cur][lane];
        float m = v;
        #pragma unroll
        for (int off = 1; off < 64; off <<= 1)
            m = fmaxf(m, __shfl_xor(m, off, 64));
        float s = __expf(v - m);
        #pragma unroll
        for (int off = 1; off < 64; off <<= 1)
            s += __shfl_xor(s, off, 64);
        if (lane == 0) out[b] = m + __logf(s);
    }
}

extern "C" void kernel_launch(void* const* d_in, const int* in_sizes, int n_in,
                              void* d_out, int out_size, void* d_ws, size_t ws_size,
                              hipStream_t stream) {
    const float* theta   = (const float*)d_in[0];   // [T,B,S,S] fp32
    const int*   lengths = (const int*)d_in[1];     // [B] int32
    float*       out     = (float*)d_out;           // [B] fp32

    packed_viterbi_kernel<<<B_DIM, 1024, 0, stream>>>(theta, lengths, out);
}

// Round 2
// 661.806 us; speedup vs baseline: 1.3013x; 1.3013x over previous
//
#include <hip/hip_runtime.h>

// PackedViterbi via chunked log-semiring scan.
//   V_new[i] = lse_j(theta[t,b,i,j] + V[j]),  T=512, B=64, S=64.
// Composition of steps is a log-semiring matmul; factoring scalar maxima
// turns it into a linear-space bf16 matmul -> MFMA.
//
// Phase 1: one wave per (b, chunk of 16 steps): P_chunk = A_t15 o ... o A_t0
//   kept as EP (linear, bf16, renormalized to max=1) + log-scale p.
//   C = E_A * EP with mfma_f32_16x16x32_bf16 (whole 64x64x64 per wave).
// Phase 2: one wave per b: V <- p + v + log(EP_chunk . exp(V - v)) over
//   active chunks, then terminal logsumexp.

typedef unsigned short u16;
typedef unsigned int   u32;

constexpr int S_DIM = 64;
constexpr int KC    = 16;    // timesteps per chunk
constexpr int NCH   = 32;    // chunks per sequence (512/16)
constexpr int LDSR  = 72;    // padded LDS row stride in bf16 elems (64+8)
constexpr float A_SHIFT = 8.0f;   // exp(theta - 8): theta ~ N(0,1), max ~5.8

typedef short bf16x8 __attribute__((ext_vector_type(8)));
typedef float f32x4  __attribute__((ext_vector_type(4)));

__device__ inline u32 f2bf_bits(float x) {
    union { float f; u32 u; } v; v.f = x;
    return (v.u + 0x8000u) >> 16;      // round-to-nearest (ties away)
}
__device__ inline float bf2f(u32 bits) {
    union { float f; u32 u; } v; v.u = bits << 16;
    return v.f;
}

// ---------------------------------------------------------------- phase 1
__global__ __launch_bounds__(64, 2) void pv_phase1(
    const float* __restrict__ theta,
    const int*   __restrict__ lengths,
    u16*         __restrict__ ept,      // [B*NCH][64*64] EP^T bf16: [n][m]
    float*       __restrict__ pscale)   // [B*NCH]
{
    const int chunk = blockIdx.x;       // 0..2047
    const int b = chunk >> 5;
    const int c = chunk & 31;
    const int L = lengths[b];
    int n = L - c * KC;
    if (n <= 0) return;
    if (n > KC) n = KC;

    __shared__ u16 As[S_DIM * LDSR];    // E_A, row-major [m][k]
    __shared__ u16 Bs[S_DIM * LDSR];    // EP^T, [n][k]  (k = EP row index)

    const int lane = threadIdx.x;       // 0..63
    const int ls = lane & 15;
    const int lq = lane >> 4;

    // ---- init Bs = identity (bf16) : lane fills its own row
    {
        uint4 z; z.x = z.y = z.z = z.w = 0u;
        uint4* rowp = (uint4*)&Bs[lane * LDSR];   // 144 B = 9 x 16 B
        #pragma unroll
        for (int q = 0; q < 9; ++q) rowp[q] = z;
        Bs[lane * LDSR + lane] = 0x3F80;          // 1.0 in bf16
    }
    __syncthreads();

    // theta[t][b][i][j]: flat = t*262144 + b*4096 + i*64 + j
    const float* tb = theta + (size_t)(c * KC) * 262144 + (size_t)b * 4096;

    // prefetch s = 0 tile: per lane 16 float4; float4 #q covers
    // row = q*4 + lq, cols (ls*4 .. ls*4+3); flat offset = q*256 + lane*4
    float4 pre[16];
    #pragma unroll
    for (int q = 0; q < 16; ++q)
        pre[q] = *(const float4*)(tb + q * 256 + lane * 4);

    float logp = 0.0f;
    f32x4 acc[4][4];

    for (int s = 0; s < n; ++s) {
        // ---- stage E_A = exp(theta - A_SHIFT) into As (bf16, padded rows)
        #pragma unroll
        for (int q = 0; q < 16; ++q) {
            float4 t = pre[q];
            u32 b0 = f2bf_bits(__expf(t.x - A_SHIFT));
            u32 b1 = f2bf_bits(__expf(t.y - A_SHIFT));
            u32 b2 = f2bf_bits(__expf(t.z - A_SHIFT));
            u32 b3 = f2bf_bits(__expf(t.w - A_SHIFT));
            uint2 w; w.x = b0 | (b1 << 16); w.y = b2 | (b3 << 16);
            const int row = q * 4 + lq;
            *(uint2*)&As[row * LDSR + ls * 4] = w;
        }
        // ---- prefetch next timestep while we compute
        if (s + 1 < n) {
            const float* tn = tb + (size_t)(s + 1) * 262144;
            #pragma unroll
            for (int q = 0; q < 16; ++q)
                pre[q] = *(const float4*)(tn + q * 256 + lane * 4);
        }
        __syncthreads();   // As writes / Bs state visible before frag reads

        // ---- load B fragments (EP^T rows = EP columns, k-consecutive)
        bf16x8 bf[2][4];
        #pragma unroll
        for (int kt = 0; kt < 2; ++kt)
            #pragma unroll
            for (int nt = 0; nt < 4; ++nt)
                bf[kt][nt] = *(const bf16x8*)&Bs[(nt * 16 + ls) * LDSR + kt * 32 + lq * 8];

        #pragma unroll
        for (int mt = 0; mt < 4; ++mt)
            #pragma unroll
            for (int nt = 0; nt < 4; ++nt)
                #pragma unroll
                for (int r = 0; r < 4; ++r)
                    acc[mt][nt][r] = 0.0f;

        // ---- C = E_A * EP : 32 MFMAs
        #pragma unroll
        for (int mt = 0; mt < 4; ++mt) {
            bf16x8 af0 = *(const bf16x8*)&As[(mt * 16 + ls) * LDSR + lq * 8];
            bf16x8 af1 = *(const bf16x8*)&As[(mt * 16 + ls) * LDSR + 32 + lq * 8];
            #pragma unroll
            for (int nt = 0; nt < 4; ++nt) {
                acc[mt][nt] = __builtin_amdgcn_mfma_f32_16x16x32_bf16(
                    af0, bf[0][nt], acc[mt][nt], 0, 0, 0);
                acc[mt][nt] = __builtin_amdgcn_mfma_f32_16x16x32_bf16(
                    af1, bf[1][nt], acc[mt][nt], 0, 0, 0);
            }
        }

        // ---- exact renorm: cmax over all 4096 entries (wave-wide)
        float m = acc[0][0][0];
        #pragma unroll
        for (int mt = 0; mt < 4; ++mt)
            #pragma unroll
            for (int nt = 0; nt < 4; ++nt) {
                f32x4 a4 = acc[mt][nt];
                m = fmaxf(m, fmaxf(fmaxf(a4[0], a4[1]), fmaxf(a4[2], a4[3])));
            }
        #pragma unroll
        for (int off = 1; off < 64; off <<= 1)
            m = fmaxf(m, __shfl_xor(m, off, 64));

        const float inv = 1.0f / m;
        logp += A_SHIFT + __logf(m);

        __syncthreads();   // frag reads done before Bs is overwritten

        // C/D layout: col n = nt*16+ls, row m = mt*16 + lq*4 + r
        if (s + 1 < n) {
            // write normalized product back to Bs as EP^T[n][m]
            #pragma unroll
            for (int mt = 0; mt < 4; ++mt)
                #pragma unroll
                for (int nt = 0; nt < 4; ++nt) {
                    f32x4 a4 = acc[mt][nt];
                    u32 c0 = f2bf_bits(a4[0] * inv);
                    u32 c1 = f2bf_bits(a4[1] * inv);
                    u32 c2 = f2bf_bits(a4[2] * inv);
                    u32 c3 = f2bf_bits(a4[3] * inv);
                    uint2 w; w.x = c0 | (c1 << 16); w.y = c2 | (c3 << 16);
                    *(uint2*)&Bs[(nt * 16 + ls) * LDSR + mt * 16 + lq * 4] = w;
                }
        } else {
            // final: store EP^T to global
            u16* outp = ept + ((size_t)chunk << 12);
            #pragma unroll
            for (int mt = 0; mt < 4; ++mt)
                #pragma unroll
                for (int nt = 0; nt < 4; ++nt) {
                    f32x4 a4 = acc[mt][nt];
                    u32 c0 = f2bf_bits(a4[0] * inv);
                    u32 c1 = f2bf_bits(a4[1] * inv);
                    u32 c2 = f2bf_bits(a4[2] * inv);
                    u32 c3 = f2bf_bits(a4[3] * inv);
                    uint2 w; w.x = c0 | (c1 << 16); w.y = c2 | (c3 << 16);
                    *(uint2*)&outp[(nt * 16 + ls) * 64 + mt * 16 + lq * 4] = w;
                }
            if (lane == 0) pscale[chunk] = logp;
        }
    }
}

// ---------------------------------------------------------------- phase 2
__global__ __launch_bounds__(64, 1) void pv_phase2(
    const u16*   __restrict__ ept,
    const float* __restrict__ pscale,
    const int*   __restrict__ lengths,
    float*       __restrict__ out)
{
    const int b = blockIdx.x;
    const int lane = threadIdx.x;
    const int L = lengths[b];
    const int nc = (L + KC - 1) / KC;

    __shared__ float evs[S_DIM];
    float V = 0.0f;

    for (int c = 0; c < nc; ++c) {
        // lane i needs EP row i = EP^T column i; issue loads before the
        // V-dependent softmax so latency overlaps the shfl/exp chain.
        const u16* M = ept + ((size_t)(b * NCH + c) << 12);
        u32 raw[64];
        #pragma unroll
        for (int j = 0; j < 64; ++j)
            raw[j] = (u32)M[j * 64 + lane];     // EP^T[j][lane] = EP[lane][j]

        float vmax = V;
        #pragma unroll
        for (int off = 1; off < 64; off <<= 1)
            vmax = fmaxf(vmax, __shfl_xor(vmax, off, 64));
        evs[lane] = __expf(V - vmax);
        __syncthreads();

        float ev[64];
        #pragma unroll
        for (int q = 0; q < 16; ++q) {
            float4 e4 = *(const float4*)&evs[q * 4];   // broadcast reads
            ev[q * 4 + 0] = e4.x; ev[q * 4 + 1] = e4.y;
            ev[q * 4 + 2] = e4.z; ev[q * 4 + 3] = e4.w;
        }

        float y0 = 0.f, y1 = 0.f, y2 = 0.f, y3 = 0.f;
        #pragma unroll
        for (int j = 0; j < 64; j += 4) {
            y0 += bf2f(raw[j + 0]) * ev[j + 0];
            y1 += bf2f(raw[j + 1]) * ev[j + 1];
            y2 += bf2f(raw[j + 2]) * ev[j + 2];
            y3 += bf2f(raw[j + 3]) * ev[j + 3];
        }
        const float y = (y0 + y1) + (y2 + y3);
        V = pscale[b * NCH + c] + vmax + __logf(y);
        __syncthreads();   // evs WAR before next iteration
    }

    // terminal logsumexp over states
    float vmax = V;
    #pragma unroll
    for (int off = 1; off < 64; off <<= 1)
        vmax = fmaxf(vmax, __shfl_xor(vmax, off, 64));
    float ssum = __expf(V - vmax);
    #pragma unroll
    for (int off = 1; off < 64; off <<= 1)
        ssum += __shfl_xor(ssum, off, 64);
    if (lane == 0) out[b] = vmax + __logf(ssum);
}

// ---------------------------------------------------------------- launch
extern "C" void kernel_launch(void* const* d_in, const int* in_sizes, int n_in,
                              void* d_out, int out_size, void* d_ws, size_t ws_size,
                              hipStream_t stream) {
    const float* theta   = (const float*)d_in[0];   // [512,64,64,64] fp32
    const int*   lengths = (const int*)d_in[1];     // [64] int32
    float*       out     = (float*)d_out;           // [64] fp32

    // workspace: EP^T bf16 [2048][4096] (16.78 MB) + pscale [2048] fp32
    u16*   ept    = (u16*)d_ws;
    float* pscale = (float*)((char*)d_ws + (size_t)2048 * 4096 * sizeof(u16));

    pv_phase1<<<64 * NCH, 64, 0, stream>>>(theta, lengths, ept, pscale);
    pv_phase2<<<64, 64, 0, stream>>>(ept, pscale, lengths, out);
}